// Round 3
// baseline (55388.422 us; speedup 1.0000x reference)
//
#include <hip/hip_runtime.h>
#include <cmath>

// ---------------------------------------------------------------------------
// LPCNet-style vocoder on MI355X — round 8: same-XCD L2 mailbox (sc0).
// R6/R7 post-mortem: three different exchange structures all pin at
// ~3.1us/step; the shared invariant is ONE agent-scope (sc1) mailbox round
// trip per step. sc1 ops bypass the per-XCD L2 to the device coherence
// point (WRITE_SIZE == exact post volume proves it) and its visibility
// latency (~2.5us) IS the step time. R8 keeps the R6/R7 dataflow but moves
// the mailbox into the XCD-shared L2:
//   * All 8 blocks of a batch share bid%8 -> same XCD (round-robin
//     dispatch) -> same L2. sc0-only stores/loads are L1-bypassing and
//     L2-coherent -> ~200cy visibility instead of ~2.5us.
//   * No XCD scope exists in HIP -> mailbox ops are inline asm:
//     global_store_dwordx2 / global_load_dwordx2 with sc0.
//   * XCD placement is NOT guaranteed -> producer dual-posts each value:
//     fast slot (sc0, L2) + slow slot (sc0 sc1, device-visible); consumer
//     polls fast, falls back to slow every 8th retry. Wrong placement
//     degrades to R7 speed instead of deadlocking.
//   * 8B aligned single-lane stores don't tear -> {tag,data} packing safe.
// Everything else (gh-exchange topology, redundant gates on all CUs, raw
// lgkm-only barriers, LDS gic staging, padded pl) unchanged from R7.
// ---------------------------------------------------------------------------

#define NB 8
#define NF 64
#define ND 20
#define NH 256
#define NG 768      // 3*NH
#define FS 160
#define NT (NF * FS)   // 10240
#define NSLOT 768      // gh slots per parity: [gate*256 + unit]

#define HLAY(c) ((((c) >> 4) * 20) + ((c) & 15))   // 16-float groups, 20-float stride

#define AG_W(dst, src) asm volatile("v_accvgpr_write_b32 %0, %1" : "=a"(dst) : "v"(src))
#define AG_R(dst, src) asm volatile("v_accvgpr_read_b32 %0, %1" : "=v"(dst) : "a"(src))
#define VPIN(dst, src) asm volatile("v_mov_b32 %0, %1" : "=v"(dst) : "v"(src))

// Raw barrier: LDS-visibility only (no vmcnt drain; in-flight vmem rides
// across; its waits land at first use).
#define BAR() do { \
    __builtin_amdgcn_sched_barrier(0); \
    asm volatile("s_waitcnt lgkmcnt(0)" ::: "memory"); \
    __builtin_amdgcn_s_barrier(); \
    __builtin_amdgcn_sched_barrier(0); } while (0)

// 8B mailbox primitives. sc0 = L1-bypass, L2-coherent (same-XCD visible).
// sc0 sc1 = device-visible (coherence point).
static __device__ __forceinline__ unsigned long long ld8_fast(const unsigned long long* p) {
    unsigned long long v;
    asm volatile("global_load_dwordx2 %0, %1, off sc0\n\ts_waitcnt vmcnt(0)"
                 : "=v"(v) : "v"(p) : "memory");
    return v;
}
static __device__ __forceinline__ unsigned long long ld8_slow(const unsigned long long* p) {
    unsigned long long v;
    asm volatile("global_load_dwordx2 %0, %1, off sc0 sc1\n\ts_waitcnt vmcnt(0)"
                 : "=v"(v) : "v"(p) : "memory");
    return v;
}

// ---------------------------------------------------------------------------
// Kernel A: FrameRateNet + gi_cond precompute (unchanged, passing).
// ---------------------------------------------------------------------------
__global__ __launch_bounds__(128) void frn_kernel(
    const float* __restrict__ feat,
    const float* __restrict__ w1,
    const float* __restrict__ b1,
    const float* __restrict__ w2,
    const float* __restrict__ b2,
    const float* __restrict__ fw1,
    const float* __restrict__ fb1,
    const float* __restrict__ fw2,
    const float* __restrict__ fb2,
    const float* __restrict__ wi,
    const float* __restrict__ bi,
    float* __restrict__ gic)
{
    const int bf = blockIdx.x;
    const int b = bf >> 6;
    const int f = bf & 63;
    const int o = threadIdx.x;

    __shared__ float sfeat[5][ND];
    __shared__ float sc1[3][128];
    __shared__ float sc2[128];
    __shared__ float sc3[128];
    __shared__ float scond[128];

    for (int i = o; i < 5 * ND; i += 128) {
        int ff = f - 2 + i / ND;
        int c = i % ND;
        sfeat[i / ND][c] = (ff >= 0 && ff < NF) ? feat[((size_t)b * NF + ff) * ND + c] : 0.f;
    }
    __syncthreads();

    for (int df = 0; df < 3; ++df) {
        int fp = f - 1 + df;
        if (fp >= 0 && fp < NF) {
            float acc = b1[o];
            for (int k = 0; k < 3; ++k)
                for (int c = 0; c < ND; ++c)
                    acc += sfeat[df + k][c] * w1[(k * ND + c) * 128 + o];
            sc1[df][o] = tanhf(acc);
        } else {
            sc1[df][o] = 0.f;
        }
    }
    __syncthreads();

    {
        float acc = b2[o];
        for (int k = 0; k < 3; ++k)
            for (int c = 0; c < 128; ++c)
                acc += sc1[k][c] * w2[(k * 128 + c) * 128 + o];
        sc2[o] = tanhf(acc);
    }
    __syncthreads();
    {
        float acc = fb1[o];
        for (int c = 0; c < 128; ++c) acc += sc2[c] * fw1[c * 128 + o];
        sc3[o] = tanhf(acc);
    }
    __syncthreads();
    {
        float acc = fb2[o];
        for (int c = 0; c < 128; ++c) acc += sc3[c] * fw2[c * 128 + o];
        scond[o] = tanhf(acc);
    }
    __syncthreads();

    for (int r = 0; r < 6; ++r) {
        int j = o + 128 * r;
        float acc = bi[j];
        const float* wr = wi + (size_t)j * 129 + 1;
        for (int c = 0; c < 128; ++c) acc += scond[c] * wr[c];
        gic[(size_t)bf * NG + j] = acc;
    }
}

// ---------------------------------------------------------------------------
// Kernel B: AR loop. 64 blocks (b = bid&7, j = bid>>3), 512 threads.
// ---------------------------------------------------------------------------
__global__ __launch_bounds__(512, 2) void ar_kernel(
    const float* __restrict__ gic,    // (8*64, 768)
    const float* __restrict__ wh,     // (768,256) fp32
    const float* __restrict__ ow,     // (256,256) [c][o] native
    const float* __restrict__ wi,     // (768,129) — need column 0
    const float* __restrict__ bh,     // (768,)
    const float* __restrict__ ob,     // (256,)
    float* __restrict__ wav_out,      // (8, 10240)
    float* __restrict__ logits_out,   // (8, 10240, 256)
    unsigned long long* __restrict__ hxf,  // [8][2][768] fast (L2) mailbox
    unsigned long long* __restrict__ hxs)  // [8][2][768] slow (device) mailbox
{
    const int bid = blockIdx.x;
    const int b = bid & 7;            // batch (bid%8 -> same-XCD heuristic)
    const int j = bid >> 3;           // CU index within batch, 0..7
    const int t = threadIdx.x;
    const int qq = t >> 4;            // 0..31: local gh row (unit 32j+qq)
    const int ss = t & 15;            // K-chunk of 16 cols (low 4 lane bits)
    const int og = t >> 3;            // 0..63: o-group of 4 (pl)
    const int c8 = t & 7;             // c-chunk of 32 (pl)

    __shared__ __align__(16) float hsp[16 * 20];   // h (full, local), skewed
    __shared__ __align__(16) float pl[8][260];     // logits partials, +4 pad
    __shared__ float sgi[NG];                      // gic frame stage
    __shared__ float candv[4];
    __shared__ int   candi[4];

    // ---- W_h share -> 48 AGPRs: rows {g, g+256, g+512}, g=32j+qq ----
    float A0[16], A1[16], A2[16];
    {
        const float4* wb = (const float4*)wh;      // row = 64 float4
        size_t r0 = (size_t)(32 * j + qq) * 64 + ss * 4;
        #pragma unroll
        for (int i = 0; i < 4; ++i) {
            float4 x0 = wb[r0 + i];
            AG_W(A0[4*i+0], x0.x); AG_W(A0[4*i+1], x0.y);
            AG_W(A0[4*i+2], x0.z); AG_W(A0[4*i+3], x0.w);
        }
        #pragma unroll
        for (int i = 0; i < 4; ++i) {
            float4 x1 = wb[r0 + 256 * 64 + i];
            AG_W(A1[4*i+0], x1.x); AG_W(A1[4*i+1], x1.y);
            AG_W(A1[4*i+2], x1.z); AG_W(A1[4*i+3], x1.w);
        }
        #pragma unroll
        for (int i = 0; i < 4; ++i) {
            float4 x2 = wb[r0 + 512 * 64 + i];
            AG_W(A2[4*i+0], x2.x); AG_W(A2[4*i+1], x2.y);
            AG_W(A2[4*i+2], x2.z); AG_W(A2[4*i+3], x2.w);
        }
    }
    // ---- FULL out_w -> 128 pinned VGPRs: OW4[i] = ow[c8*32+i][og*4..+3] ----
    float4 OW4[32];
    {
        const float4* op = (const float4*)ow;      // row c = 64 float4
        #pragma unroll
        for (int i = 0; i < 32; ++i) {
            float4 x = op[(size_t)(c8 * 32 + i) * 64 + og];
            VPIN(OW4[i].x, x.x); VPIN(OW4[i].y, x.y);
            VPIN(OW4[i].z, x.z); VPIN(OW4[i].w, x.w);
        }
    }

    // ---- per-thread scalars: thread t<256 owns gate unit u=t in D ----
    float bh_r = 0, bh_z = 0, bh_n = 0, wi_r = 0, wi_z = 0, wi_n = 0, ob_o = 0;
    if (t < NH) {
        bh_r = bh[t]; bh_z = bh[t + 256]; bh_n = bh[t + 512];
        wi_r = wi[(size_t)t * 129];
        wi_z = wi[(size_t)(t + 256) * 129];
        wi_n = wi[(size_t)(t + 512) * 129];
        ob_o = ob[t];
        hsp[HLAY(t)] = 0.f;
    }
    float prev = 0.f, yacc = 0.f;
    __syncthreads();

    const float* gf = gic + (size_t)b * NF * NG;   // advances per frame
    float* lob = logits_out + (size_t)b * NT * NH;
    float* wob = wav_out + (size_t)b * NT;
    unsigned long long* hxfb = hxf + (size_t)b * 2 * NSLOT;
    unsigned long long* hxsb = hxs + (size_t)b * 2 * NSLOT;
    int fcnt = 0;

    for (int st = 0; st <= NT; ++st) {
        // ---- frame staging: gic -> LDS once per 160 steps ----
        if (st < NT && fcnt == 0) {
            for (int i = t; i < NG; i += 512) sgi[i] = gf[i];
        }

        // ---- Phase A1: gh rows for own 32 units; dual-post (tag st+1) ----
        if (st < NT) {
            const float4* h4 = (const float4*)hsp;
            float a0 = 0.f, a1 = 0.f, a2 = 0.f;
            #pragma unroll
            for (int i = 0; i < 4; ++i) {
                float4 hv = h4[ss * 5 + i];
                float w;
                AG_R(w, A0[4*i+0]); a0 += w * hv.x;
                AG_R(w, A0[4*i+1]); a0 += w * hv.y;
                AG_R(w, A0[4*i+2]); a0 += w * hv.z;
                AG_R(w, A0[4*i+3]); a0 += w * hv.w;
                AG_R(w, A1[4*i+0]); a1 += w * hv.x;
                AG_R(w, A1[4*i+1]); a1 += w * hv.y;
                AG_R(w, A1[4*i+2]); a1 += w * hv.z;
                AG_R(w, A1[4*i+3]); a1 += w * hv.w;
                AG_R(w, A2[4*i+0]); a2 += w * hv.x;
                AG_R(w, A2[4*i+1]); a2 += w * hv.y;
                AG_R(w, A2[4*i+2]); a2 += w * hv.z;
                AG_R(w, A2[4*i+3]); a2 += w * hv.w;
            }
            #pragma unroll
            for (int d = 1; d <= 8; d <<= 1) {
                a0 += __shfl_xor(a0, d);
                a1 += __shfl_xor(a1, d);
                a2 += __shfl_xor(a2, d);
            }
            if (ss < 3) {
                float gv = (ss == 0) ? a0 : ((ss == 1) ? a1 : a2);
                unsigned long long pk =
                    ((unsigned long long)(unsigned)(st + 1) << 32)
                    | (unsigned long long)__float_as_uint(gv);
                size_t slot = (size_t)(st & 1) * NSLOT + (ss << 8) + 32 * j + qq;
                // fast: L2-coherent (same-XCD); slow: device-visible fallback
                asm volatile(
                    "global_store_dwordx2 %0, %2, off sc0\n\t"
                    "global_store_dwordx2 %1, %2, off sc0 sc1"
                    :: "v"(hxfb + slot), "v"(hxsb + slot), "v"(pk)
                    : "memory");
            }
            __builtin_amdgcn_sched_barrier(0);   // keep posts ahead of pl work
        }

        // ---- Phase A2: logits partials for h_{st-1} (runs at st==NT too) ----
        if (st > 0) {
            const float4* h4 = (const float4*)hsp;
            float4 acc = {0.f, 0.f, 0.f, 0.f};
            #pragma unroll
            for (int i = 0; i < 8; ++i) {
                float4 hv = h4[(c8 * 2 + (i >> 2)) * 5 + (i & 3)];
                acc.x += hv.x * OW4[4*i+0].x; acc.y += hv.x * OW4[4*i+0].y;
                acc.z += hv.x * OW4[4*i+0].z; acc.w += hv.x * OW4[4*i+0].w;
                acc.x += hv.y * OW4[4*i+1].x; acc.y += hv.y * OW4[4*i+1].y;
                acc.z += hv.y * OW4[4*i+1].z; acc.w += hv.y * OW4[4*i+1].w;
                acc.x += hv.z * OW4[4*i+2].x; acc.y += hv.z * OW4[4*i+2].y;
                acc.z += hv.z * OW4[4*i+2].z; acc.w += hv.z * OW4[4*i+2].w;
                acc.x += hv.w * OW4[4*i+3].x; acc.y += hv.w * OW4[4*i+3].y;
                acc.z += hv.w * OW4[4*i+3].z; acc.w += hv.w * OW4[4*i+3].w;
            }
            *(float4*)&pl[c8][og * 4] = acc;
        }
        BAR();   // b1 (LDS only; posts stay in flight)

        // ---- preload gh (fast slots): L2 latency hides under B+C ----
        unsigned long long g0 = 0, g1 = 0, g2 = 0;
        if (st < NT && t < NH) {
            const unsigned long long* hb = hxfb + (size_t)(st & 1) * NSLOT;
            asm volatile(
                "global_load_dwordx2 %0, %3, off sc0\n\t"
                "global_load_dwordx2 %1, %4, off sc0\n\t"
                "global_load_dwordx2 %2, %5, off sc0"
                : "=&v"(g0), "=&v"(g1), "=&v"(g2)
                : "v"(hb + t), "v"(hb + NH + t), "v"(hb + 2 * NH + t)
                : "memory");
        }

        // ---- Phase B: finalize logits, store own slice, wave argmax ----
        if (st > 0 && t < NH) {
            float lg = ob_o;
            #pragma unroll
            for (int c = 0; c < 8; ++c) lg += pl[c][t];
            if ((t >> 5) == j) lob[(size_t)(st - 1) * NH + t] = lg;
            float bv = lg; int bi_ = t;
            #pragma unroll
            for (int d = 32; d > 0; d >>= 1) {
                float ov = __shfl_down(bv, d);
                int   oi = __shfl_down(bi_, d);
                if (ov > bv || (ov == bv && oi < bi_)) { bv = ov; bi_ = oi; }
            }
            if ((t & 63) == 0) { candv[t >> 6] = bv; candi[t >> 6] = bi_; }
        }
        BAR();   // b2

        // ---- Phase C: sample (all threads, identical everywhere) ----
        if (st > 0) {
            float mv = candv[0]; int mi = candi[0];
            #pragma unroll
            for (int w = 1; w < 4; ++w) {
                float ov = candv[w]; int oi = candi[w];
                if (ov > mv || (ov == mv && oi < mi)) { mv = ov; mi = oi; }
            }
            float v = ((float)mi + 0.5f) * (1.f / 128.f) - 1.f;
            float av = fabsf(v);
            float mag = (exp2f(8.f * av) - 1.f) * (1.f / 255.f);
            float smp = (v >= 0.f) ? mag : -mag;
            prev = smp;
            yacc = smp + 0.97f * yacc;
            if (j == 0 && t == 0) wob[st - 1] = yacc;
        }

        // ---- Phase D: ALL 256 gate units, redundantly on every CU ----
        if (st < NT && t < NH) {
            const unsigned tag = (unsigned)(st + 1);
            const unsigned long long* hf = hxfb + (size_t)(st & 1) * NSLOT;
            const unsigned long long* hs = hxsb + (size_t)(st & 1) * NSLOT;
            // materialize the preloads (rule #18: fence + sched_barrier)
            asm volatile("s_waitcnt vmcnt(0)"
                         : "+v"(g0), "+v"(g1), "+v"(g2) :: "memory");
            __builtin_amdgcn_sched_barrier(0);
            int spin = 0;
            while (((unsigned)(g0 >> 32) != tag) |
                   ((unsigned)(g1 >> 32) != tag) |
                   ((unsigned)(g2 >> 32) != tag)) {
                ++spin;
                bool slow = (spin & 7) == 7;   // liveness: check device copy
                if ((unsigned)(g0 >> 32) != tag)
                    g0 = slow ? ld8_slow(hs + t) : ld8_fast(hf + t);
                if ((unsigned)(g1 >> 32) != tag)
                    g1 = slow ? ld8_slow(hs + NH + t) : ld8_fast(hf + NH + t);
                if ((unsigned)(g2 >> 32) != tag)
                    g2 = slow ? ld8_slow(hs + 2 * NH + t) : ld8_fast(hf + 2 * NH + t);
                if (slow) __builtin_amdgcn_s_sleep(1);
            }
            float ghr = __uint_as_float((unsigned)g0);
            float ghz = __uint_as_float((unsigned)g1);
            float ghn = __uint_as_float((unsigned)g2);
            float sr = sgi[t]          + wi_r * prev + bh_r + ghr;
            float sz = sgi[t + NH]     + wi_z * prev + bh_z + ghz;
            float ni = sgi[t + 2 * NH] + wi_n * prev;
            float nh = bh_n + ghn;
            float r = 1.f / (1.f + expf(-sr));
            float z = 1.f / (1.f + expf(-sz));
            float n = tanhf(ni + r * nh);
            int hl = HLAY(t);
            hsp[hl] = (1.f - z) * n + z * hsp[hl];
        }
        BAR();   // b3

        if (st < NT) {
            if (++fcnt == FS) { fcnt = 0; gf += NG; }
        }
    }
}

// ---------------------------------------------------------------------------
extern "C" void kernel_launch(void* const* d_in, const int* in_sizes, int n_in,
                              void* d_out, int out_size, void* d_ws, size_t ws_size,
                              hipStream_t stream) {
    (void)in_sizes; (void)n_in; (void)out_size; (void)ws_size;

    const float* feat = (const float*)d_in[0];
    const float* c1w  = (const float*)d_in[1];
    const float* c1b  = (const float*)d_in[2];
    const float* c2w  = (const float*)d_in[3];
    const float* c2b  = (const float*)d_in[4];
    const float* f1w  = (const float*)d_in[5];
    const float* f1b  = (const float*)d_in[6];
    const float* f2w  = (const float*)d_in[7];
    const float* f2b  = (const float*)d_in[8];
    const float* gwi  = (const float*)d_in[9];
    const float* gwh  = (const float*)d_in[10];
    const float* gbi  = (const float*)d_in[11];
    const float* gbh  = (const float*)d_in[12];
    const float* outw = (const float*)d_in[13];
    const float* outb = (const float*)d_in[14];

    // workspace layout
    char* ws = (char*)d_ws;
    float* gic = (float*)ws;                                        // 1,572,864 B
    unsigned long long* hxf = (unsigned long long*)(ws + 1572864);  // 98,304 B fast
    unsigned long long* hxs = (unsigned long long*)(ws + 1671168);  // 98,304 B slow
    // tag protocol: harness poison (0xAA bytes) never matches any tag
    // (st+1 <= 10240); stale same-tag data from a prior identical launch is
    // bitwise identical (deterministic compute), so no memset is required.

    float* wav    = (float*)d_out;                 // (8,10240,1)
    float* logits = (float*)d_out + NB * NT;       // (8,10240,256)

    frn_kernel<<<dim3(NB * NF), dim3(128), 0, stream>>>(
        feat, c1w, c1b, c2w, c2b, f1w, f1b, f2w, f2b, gwi, gbi, gic);
    ar_kernel<<<dim3(64), dim3(512), 0, stream>>>(
        gic, gwh, outw, gwi, gbh, outb, wav, logits, hxf, hxs);
}

// Round 4
// 32772.495 us; speedup vs baseline: 1.6901x; 1.6901x over previous
//
#include <hip/hip_runtime.h>
#include <cmath>

// ---------------------------------------------------------------------------
// LPCNet-style vocoder on MI355X — round 9: L2 mailbox via atomic-RMW polls.
// R8 post-mortem: sc0-only LOADS do not bypass L1 on gfx950 -> consumers
// re-read their own stale (incoherent) L1 line; every step burned ~7 dead
// fast polls before the slow fallback rescued it (dur 32->55ms, VALU*time
// const = pure added wait). The L2-mailbox idea is untested, the mechanism
// was wrong. R9 uses mechanisms that CANNOT hit stale L1:
//   * Consumer poll = global_atomic_or_x2 with 0, sc0 (return-old). AMD L1
//     is read-only: atomics ALWAYS execute at L2+ -> guaranteed fresh read
//     at the local XCD L2.
//   * Producer fast post = PLAIN global_store_dwordx2 (write-through L1 ->
//     local L2; vmcnt ack = at L2). Same XCD (bid%8 heuristic) -> same L2
//     -> ~200-400cy visibility instead of ~5000cy coherence-point trip.
//   * Placement not guaranteed -> dual-post to device-visible (sc0 sc1)
//     slow mailbox kept; spin falls back to it every 3rd retry (worst case
//     ~ R7 + 700cy, not R8's 8-dead-polls). Tag check makes stale reads
//     safe; fallback guarantees liveness.
//   * Producer vmcnt(0) drain after A2 reinstated (R7) -> posts at L2/L3
//     before consumers preload.
// Decisive fork: FETCH collapse + dur collapse = latency theory confirmed;
// FETCH collapse + dur flat = issue/clock-bound -> pivot next round.
// Everything else (gh-exchange topology, redundant gates, lgkm-only
// barriers, LDS gic staging, padded pl) unchanged from R7.
// ---------------------------------------------------------------------------

#define NB 8
#define NF 64
#define ND 20
#define NH 256
#define NG 768      // 3*NH
#define FS 160
#define NT (NF * FS)   // 10240
#define NSLOT 768      // gh slots per parity: [gate*256 + unit]

#define HLAY(c) ((((c) >> 4) * 20) + ((c) & 15))   // 16-float groups, 20-float stride

#define AG_W(dst, src) asm volatile("v_accvgpr_write_b32 %0, %1" : "=a"(dst) : "v"(src))
#define AG_R(dst, src) asm volatile("v_accvgpr_read_b32 %0, %1" : "=v"(dst) : "a"(src))
#define VPIN(dst, src) asm volatile("v_mov_b32 %0, %1" : "=v"(dst) : "v"(src))

// Raw barrier: LDS-visibility only (no vmcnt drain; in-flight vmem rides
// across; its waits land at first use).
#define BAR() do { \
    __builtin_amdgcn_sched_barrier(0); \
    asm volatile("s_waitcnt lgkmcnt(0)" ::: "memory"); \
    __builtin_amdgcn_s_barrier(); \
    __builtin_amdgcn_sched_barrier(0); } while (0)

// Fresh read at the local L2: atomic OR with 0, sc0 = return old value.
// Atomics never execute in L1 -> cannot see a stale line.
static __device__ __forceinline__ unsigned long long or0_fast(
    unsigned long long* p, unsigned long long z) {
    unsigned long long v;
    asm volatile("global_atomic_or_x2 %0, %1, %2, off sc0\n\t"
                 "s_waitcnt vmcnt(0)"
                 : "=&v"(v) : "v"(p), "v"(z) : "memory");
    return v;
}
// Device-coherent read (coherence point) — liveness fallback.
static __device__ __forceinline__ unsigned long long ld8_slow(
    const unsigned long long* p) {
    unsigned long long v;
    asm volatile("global_load_dwordx2 %0, %1, off sc0 sc1\n\t"
                 "s_waitcnt vmcnt(0)"
                 : "=v"(v) : "v"(p) : "memory");
    return v;
}

// ---------------------------------------------------------------------------
// Kernel A: FrameRateNet + gi_cond precompute (unchanged, passing).
// ---------------------------------------------------------------------------
__global__ __launch_bounds__(128) void frn_kernel(
    const float* __restrict__ feat,
    const float* __restrict__ w1,
    const float* __restrict__ b1,
    const float* __restrict__ w2,
    const float* __restrict__ b2,
    const float* __restrict__ fw1,
    const float* __restrict__ fb1,
    const float* __restrict__ fw2,
    const float* __restrict__ fb2,
    const float* __restrict__ wi,
    const float* __restrict__ bi,
    float* __restrict__ gic)
{
    const int bf = blockIdx.x;
    const int b = bf >> 6;
    const int f = bf & 63;
    const int o = threadIdx.x;

    __shared__ float sfeat[5][ND];
    __shared__ float sc1[3][128];
    __shared__ float sc2[128];
    __shared__ float sc3[128];
    __shared__ float scond[128];

    for (int i = o; i < 5 * ND; i += 128) {
        int ff = f - 2 + i / ND;
        int c = i % ND;
        sfeat[i / ND][c] = (ff >= 0 && ff < NF) ? feat[((size_t)b * NF + ff) * ND + c] : 0.f;
    }
    __syncthreads();

    for (int df = 0; df < 3; ++df) {
        int fp = f - 1 + df;
        if (fp >= 0 && fp < NF) {
            float acc = b1[o];
            for (int k = 0; k < 3; ++k)
                for (int c = 0; c < ND; ++c)
                    acc += sfeat[df + k][c] * w1[(k * ND + c) * 128 + o];
            sc1[df][o] = tanhf(acc);
        } else {
            sc1[df][o] = 0.f;
        }
    }
    __syncthreads();

    {
        float acc = b2[o];
        for (int k = 0; k < 3; ++k)
            for (int c = 0; c < 128; ++c)
                acc += sc1[k][c] * w2[(k * 128 + c) * 128 + o];
        sc2[o] = tanhf(acc);
    }
    __syncthreads();
    {
        float acc = fb1[o];
        for (int c = 0; c < 128; ++c) acc += sc2[c] * fw1[c * 128 + o];
        sc3[o] = tanhf(acc);
    }
    __syncthreads();
    {
        float acc = fb2[o];
        for (int c = 0; c < 128; ++c) acc += sc3[c] * fw2[c * 128 + o];
        scond[o] = tanhf(acc);
    }
    __syncthreads();

    for (int r = 0; r < 6; ++r) {
        int j = o + 128 * r;
        float acc = bi[j];
        const float* wr = wi + (size_t)j * 129 + 1;
        for (int c = 0; c < 128; ++c) acc += scond[c] * wr[c];
        gic[(size_t)bf * NG + j] = acc;
    }
}

// ---------------------------------------------------------------------------
// Kernel B: AR loop. 64 blocks (b = bid&7, j = bid>>3), 512 threads.
// ---------------------------------------------------------------------------
__global__ __launch_bounds__(512, 2) void ar_kernel(
    const float* __restrict__ gic,    // (8*64, 768)
    const float* __restrict__ wh,     // (768,256) fp32
    const float* __restrict__ ow,     // (256,256) [c][o] native
    const float* __restrict__ wi,     // (768,129) — need column 0
    const float* __restrict__ bh,     // (768,)
    const float* __restrict__ ob,     // (256,)
    float* __restrict__ wav_out,      // (8, 10240)
    float* __restrict__ logits_out,   // (8, 10240, 256)
    unsigned long long* __restrict__ hxf,  // [8][2][768] fast (local-L2) mailbox
    unsigned long long* __restrict__ hxs)  // [8][2][768] slow (device) mailbox
{
    const int bid = blockIdx.x;
    const int b = bid & 7;            // batch (bid%8 -> same-XCD heuristic)
    const int j = bid >> 3;           // CU index within batch, 0..7
    const int t = threadIdx.x;
    const int qq = t >> 4;            // 0..31: local gh row (unit 32j+qq)
    const int ss = t & 15;            // K-chunk of 16 cols (low 4 lane bits)
    const int og = t >> 3;            // 0..63: o-group of 4 (pl)
    const int c8 = t & 7;             // c-chunk of 32 (pl)

    __shared__ __align__(16) float hsp[16 * 20];   // h (full, local), skewed
    __shared__ __align__(16) float pl[8][260];     // logits partials, +4 pad
    __shared__ float sgi[NG];                      // gic frame stage
    __shared__ float candv[4];
    __shared__ int   candi[4];

    // ---- W_h share -> 48 AGPRs: rows {g, g+256, g+512}, g=32j+qq ----
    float A0[16], A1[16], A2[16];
    {
        const float4* wb = (const float4*)wh;      // row = 64 float4
        size_t r0 = (size_t)(32 * j + qq) * 64 + ss * 4;
        #pragma unroll
        for (int i = 0; i < 4; ++i) {
            float4 x0 = wb[r0 + i];
            AG_W(A0[4*i+0], x0.x); AG_W(A0[4*i+1], x0.y);
            AG_W(A0[4*i+2], x0.z); AG_W(A0[4*i+3], x0.w);
        }
        #pragma unroll
        for (int i = 0; i < 4; ++i) {
            float4 x1 = wb[r0 + 256 * 64 + i];
            AG_W(A1[4*i+0], x1.x); AG_W(A1[4*i+1], x1.y);
            AG_W(A1[4*i+2], x1.z); AG_W(A1[4*i+3], x1.w);
        }
        #pragma unroll
        for (int i = 0; i < 4; ++i) {
            float4 x2 = wb[r0 + 512 * 64 + i];
            AG_W(A2[4*i+0], x2.x); AG_W(A2[4*i+1], x2.y);
            AG_W(A2[4*i+2], x2.z); AG_W(A2[4*i+3], x2.w);
        }
    }
    // ---- FULL out_w -> 128 pinned VGPRs: OW4[i] = ow[c8*32+i][og*4..+3] ----
    float4 OW4[32];
    {
        const float4* op = (const float4*)ow;      // row c = 64 float4
        #pragma unroll
        for (int i = 0; i < 32; ++i) {
            float4 x = op[(size_t)(c8 * 32 + i) * 64 + og];
            VPIN(OW4[i].x, x.x); VPIN(OW4[i].y, x.y);
            VPIN(OW4[i].z, x.z); VPIN(OW4[i].w, x.w);
        }
    }

    // ---- per-thread scalars: thread t<256 owns gate unit u=t in D ----
    float bh_r = 0, bh_z = 0, bh_n = 0, wi_r = 0, wi_z = 0, wi_n = 0, ob_o = 0;
    if (t < NH) {
        bh_r = bh[t]; bh_z = bh[t + 256]; bh_n = bh[t + 512];
        wi_r = wi[(size_t)t * 129];
        wi_z = wi[(size_t)(t + 256) * 129];
        wi_n = wi[(size_t)(t + 512) * 129];
        ob_o = ob[t];
        hsp[HLAY(t)] = 0.f;
    }
    float prev = 0.f, yacc = 0.f;
    unsigned long long zero64 = 0;
    __syncthreads();

    const float* gf = gic + (size_t)b * NF * NG;   // advances per frame
    float* lob = logits_out + (size_t)b * NT * NH;
    float* wob = wav_out + (size_t)b * NT;
    unsigned long long* hxfb = hxf + (size_t)b * 2 * NSLOT;
    unsigned long long* hxsb = hxs + (size_t)b * 2 * NSLOT;
    int fcnt = 0;

    for (int st = 0; st <= NT; ++st) {
        // ---- frame staging: gic -> LDS once per 160 steps ----
        if (st < NT && fcnt == 0) {
            for (int i = t; i < NG; i += 512) sgi[i] = gf[i];
        }

        // ---- Phase A1: gh rows for own 32 units; dual-post (tag st+1) ----
        if (st < NT) {
            const float4* h4 = (const float4*)hsp;
            float a0 = 0.f, a1 = 0.f, a2 = 0.f;
            #pragma unroll
            for (int i = 0; i < 4; ++i) {
                float4 hv = h4[ss * 5 + i];
                float w;
                AG_R(w, A0[4*i+0]); a0 += w * hv.x;
                AG_R(w, A0[4*i+1]); a0 += w * hv.y;
                AG_R(w, A0[4*i+2]); a0 += w * hv.z;
                AG_R(w, A0[4*i+3]); a0 += w * hv.w;
                AG_R(w, A1[4*i+0]); a1 += w * hv.x;
                AG_R(w, A1[4*i+1]); a1 += w * hv.y;
                AG_R(w, A1[4*i+2]); a1 += w * hv.z;
                AG_R(w, A1[4*i+3]); a1 += w * hv.w;
                AG_R(w, A2[4*i+0]); a2 += w * hv.x;
                AG_R(w, A2[4*i+1]); a2 += w * hv.y;
                AG_R(w, A2[4*i+2]); a2 += w * hv.z;
                AG_R(w, A2[4*i+3]); a2 += w * hv.w;
            }
            #pragma unroll
            for (int d = 1; d <= 8; d <<= 1) {
                a0 += __shfl_xor(a0, d);
                a1 += __shfl_xor(a1, d);
                a2 += __shfl_xor(a2, d);
            }
            if (ss < 3) {
                float gv = (ss == 0) ? a0 : ((ss == 1) ? a1 : a2);
                unsigned long long pk =
                    ((unsigned long long)(unsigned)(st + 1) << 32)
                    | (unsigned long long)__float_as_uint(gv);
                size_t slot = (size_t)(st & 1) * NSLOT + (ss << 8) + 32 * j + qq;
                // fast: plain write-through -> local XCD L2 (same-XCD
                // consumers see it at L2 latency); slow: device-visible.
                asm volatile(
                    "global_store_dwordx2 %0, %2, off\n\t"
                    "global_store_dwordx2 %1, %2, off sc0 sc1"
                    :: "v"(hxfb + slot), "v"(hxsb + slot), "v"(pk)
                    : "memory");
            }
            __builtin_amdgcn_sched_barrier(0);   // keep posts ahead of pl work
        }

        // ---- Phase A2: logits partials for h_{st-1} (runs at st==NT too) ----
        if (st > 0) {
            const float4* h4 = (const float4*)hsp;
            float4 acc = {0.f, 0.f, 0.f, 0.f};
            #pragma unroll
            for (int i = 0; i < 8; ++i) {
                float4 hv = h4[(c8 * 2 + (i >> 2)) * 5 + (i & 3)];
                acc.x += hv.x * OW4[4*i+0].x; acc.y += hv.x * OW4[4*i+0].y;
                acc.z += hv.x * OW4[4*i+0].z; acc.w += hv.x * OW4[4*i+0].w;
                acc.x += hv.y * OW4[4*i+1].x; acc.y += hv.y * OW4[4*i+1].y;
                acc.z += hv.y * OW4[4*i+1].z; acc.w += hv.y * OW4[4*i+1].w;
                acc.x += hv.z * OW4[4*i+2].x; acc.y += hv.z * OW4[4*i+2].y;
                acc.z += hv.z * OW4[4*i+2].z; acc.w += hv.z * OW4[4*i+2].w;
                acc.x += hv.w * OW4[4*i+3].x; acc.y += hv.w * OW4[4*i+3].y;
                acc.z += hv.w * OW4[4*i+3].z; acc.w += hv.w * OW4[4*i+3].w;
            }
            *(float4*)&pl[c8][og * 4] = acc;
        }
        // Drain posts (covered by A2's FMA issue): fast posts at L2, slow
        // posts at the coherence point, before consumers preload.
        if (st < NT) {
            asm volatile("s_waitcnt vmcnt(0)" ::: "memory");
        }
        BAR();   // b1 (LDS only)

        // ---- preload gh via L2-point atomic-or(0): fresh, L1-proof;
        //      latency hides under B+C; wait lands in D ----
        unsigned long long g0 = 0, g1 = 0, g2 = 0;
        if (st < NT && t < NH) {
            unsigned long long* hb = hxfb + (size_t)(st & 1) * NSLOT;
            asm volatile(
                "global_atomic_or_x2 %0, %3, %6, off sc0\n\t"
                "global_atomic_or_x2 %1, %4, %6, off sc0\n\t"
                "global_atomic_or_x2 %2, %5, %6, off sc0"
                : "=&v"(g0), "=&v"(g1), "=&v"(g2)
                : "v"(hb + t), "v"(hb + NH + t), "v"(hb + 2 * NH + t),
                  "v"(zero64)
                : "memory");
        }

        // ---- Phase B: finalize logits, store own slice, wave argmax ----
        if (st > 0 && t < NH) {
            float lg = ob_o;
            #pragma unroll
            for (int c = 0; c < 8; ++c) lg += pl[c][t];
            if ((t >> 5) == j) lob[(size_t)(st - 1) * NH + t] = lg;
            float bv = lg; int bi_ = t;
            #pragma unroll
            for (int d = 32; d > 0; d >>= 1) {
                float ov = __shfl_down(bv, d);
                int   oi = __shfl_down(bi_, d);
                if (ov > bv || (ov == bv && oi < bi_)) { bv = ov; bi_ = oi; }
            }
            if ((t & 63) == 0) { candv[t >> 6] = bv; candi[t >> 6] = bi_; }
        }
        BAR();   // b2

        // ---- Phase C: sample (all threads, identical everywhere) ----
        if (st > 0) {
            float mv = candv[0]; int mi = candi[0];
            #pragma unroll
            for (int w = 1; w < 4; ++w) {
                float ov = candv[w]; int oi = candi[w];
                if (ov > mv || (ov == mv && oi < mi)) { mv = ov; mi = oi; }
            }
            float v = ((float)mi + 0.5f) * (1.f / 128.f) - 1.f;
            float av = fabsf(v);
            float mag = (exp2f(8.f * av) - 1.f) * (1.f / 255.f);
            float smp = (v >= 0.f) ? mag : -mag;
            prev = smp;
            yacc = smp + 0.97f * yacc;
            if (j == 0 && t == 0) wob[st - 1] = yacc;
        }

        // ---- Phase D: ALL 256 gate units, redundantly on every CU ----
        if (st < NT && t < NH) {
            const unsigned tag = (unsigned)(st + 1);
            unsigned long long* hf = hxfb + (size_t)(st & 1) * NSLOT;
            const unsigned long long* hs = hxsb + (size_t)(st & 1) * NSLOT;
            // materialize the preloads (rule #18: fence + sched_barrier)
            asm volatile("s_waitcnt vmcnt(0)"
                         : "+v"(g0), "+v"(g1), "+v"(g2) :: "memory");
            __builtin_amdgcn_sched_barrier(0);
            int spin = 0;
            while (((unsigned)(g0 >> 32) != tag) |
                   ((unsigned)(g1 >> 32) != tag) |
                   ((unsigned)(g2 >> 32) != tag)) {
                ++spin;
                bool slow = (spin % 3) == 0;   // liveness: device copy
                if ((unsigned)(g0 >> 32) != tag)
                    g0 = slow ? ld8_slow(hs + t) : or0_fast(hf + t, zero64);
                if ((unsigned)(g1 >> 32) != tag)
                    g1 = slow ? ld8_slow(hs + NH + t)
                              : or0_fast(hf + NH + t, zero64);
                if ((unsigned)(g2 >> 32) != tag)
                    g2 = slow ? ld8_slow(hs + 2 * NH + t)
                              : or0_fast(hf + 2 * NH + t, zero64);
                if (slow) __builtin_amdgcn_s_sleep(1);
            }
            float ghr = __uint_as_float((unsigned)g0);
            float ghz = __uint_as_float((unsigned)g1);
            float ghn = __uint_as_float((unsigned)g2);
            float sr = sgi[t]          + wi_r * prev + bh_r + ghr;
            float sz = sgi[t + NH]     + wi_z * prev + bh_z + ghz;
            float ni = sgi[t + 2 * NH] + wi_n * prev;
            float nh = bh_n + ghn;
            float r = 1.f / (1.f + expf(-sr));
            float z = 1.f / (1.f + expf(-sz));
            float n = tanhf(ni + r * nh);
            int hl = HLAY(t);
            hsp[hl] = (1.f - z) * n + z * hsp[hl];
        }
        BAR();   // b3

        if (st < NT) {
            if (++fcnt == FS) { fcnt = 0; gf += NG; }
        }
    }
}

// ---------------------------------------------------------------------------
extern "C" void kernel_launch(void* const* d_in, const int* in_sizes, int n_in,
                              void* d_out, int out_size, void* d_ws, size_t ws_size,
                              hipStream_t stream) {
    (void)in_sizes; (void)n_in; (void)out_size; (void)ws_size;

    const float* feat = (const float*)d_in[0];
    const float* c1w  = (const float*)d_in[1];
    const float* c1b  = (const float*)d_in[2];
    const float* c2w  = (const float*)d_in[3];
    const float* c2b  = (const float*)d_in[4];
    const float* f1w  = (const float*)d_in[5];
    const float* f1b  = (const float*)d_in[6];
    const float* f2w  = (const float*)d_in[7];
    const float* f2b  = (const float*)d_in[8];
    const float* gwi  = (const float*)d_in[9];
    const float* gwh  = (const float*)d_in[10];
    const float* gbi  = (const float*)d_in[11];
    const float* gbh  = (const float*)d_in[12];
    const float* outw = (const float*)d_in[13];
    const float* outb = (const float*)d_in[14];

    // workspace layout
    char* ws = (char*)d_ws;
    float* gic = (float*)ws;                                        // 1,572,864 B
    unsigned long long* hxf = (unsigned long long*)(ws + 1572864);  // 98,304 B fast
    unsigned long long* hxs = (unsigned long long*)(ws + 1671168);  // 98,304 B slow
    // tag protocol: harness poison (0xAA bytes) never matches any tag
    // (st+1 <= 10240); stale same-tag data from a prior identical launch is
    // bitwise identical (deterministic compute), so no memset is required.

    float* wav    = (float*)d_out;                 // (8,10240,1)
    float* logits = (float*)d_out + NB * NT;       // (8,10240,256)

    frn_kernel<<<dim3(NB * NF), dim3(128), 0, stream>>>(
        feat, c1w, c1b, c2w, c2b, f1w, f1b, f2w, f2b, gwi, gbi, gic);
    ar_kernel<<<dim3(64), dim3(512), 0, stream>>>(
        gic, gwh, outw, gwi, gbh, outb, wav, logits, hxf, hxs);
}

// Round 5
// 32435.226 us; speedup vs baseline: 1.7077x; 1.0104x over previous
//
#include <hip/hip_runtime.h>
#include <cmath>

// ---------------------------------------------------------------------------
// LPCNet-style vocoder on MI355X — round 10: defer store-acks + clock probe.
// R9 post-mortem: FETCH collapsed 47x (fast L2 polls engaged) but dur FLAT ->
// mailbox visibility latency is NOT the floor (5 structures, same 3.1us/step).
// Reverted to R7's known-good single sc1 mailbox (R9's RMW polls added 5GB/s
// of dirty-line writeback for nothing).
// Two unmodeled terms remain, both shared by ALL rounds:
//  (1) store-acks inside D's wait window: lob (B) and wob (C) stores are
//      issued between the gh preloads and D's vmcnt(0) materialize -> every
//      step waits a fresh write-through-to-HBM ack. FIX: defer both stores
//      to after the gate compute (values kept in regs).
//  (2) unverified clock: at 6% occupancy a low DPM state would scale every
//      chain uniformly = the observed invariance. MEASURE: post-loop, block0
//      calibrates shader MHz via a 131072-link dependent v_fma chain (4cy
//      per link, clock-invariant cycle count) against s_memrealtime (100MHz),
//      then encodes the result into WRITE_SIZE (sc1 stores reach the HBM
//      counter 1:1 — proven by R7's exact post-volume match; FETCH is
//      L3-absorbed and unusable):
//        lines(64B) = 16*MHz + 4096 + 131072*(retries >= 1/step avg)
//      DECODE next round: dW = (WRITE_KB - ~573800)*1024; lines = dW/64;
//      flag = lines > 60000 (then lines -= 131072); MHz = (lines-4096)/16.
//      (If EA write granule is 128B not 64B, decoded MHz halves — resolve
//      against DPM-plausible states.)  dW==0 -> wssz<20MB, probes skipped.
// Also dropped: producer A2-end vmcnt drain (consumers spin on tags; the
// causal chain post(st+2) <= D(st+1) <= tags(st+1) <= D(st) prevents parity
// clobber, so the drain only serialized the producer).
// ---------------------------------------------------------------------------

#define NB 8
#define NF 64
#define ND 20
#define NH 256
#define NG 768      // 3*NH
#define FS 160
#define NT (NF * FS)   // 10240
#define NSLOT 768      // gh slots per parity: [gate*256 + unit]

#define AGENT __HIP_MEMORY_SCOPE_AGENT
#define HLAY(c) ((((c) >> 4) * 20) + ((c) & 15))   // 16-float groups, 20-float stride

#define AG_W(dst, src) asm volatile("v_accvgpr_write_b32 %0, %1" : "=a"(dst) : "v"(src))
#define AG_R(dst, src) asm volatile("v_accvgpr_read_b32 %0, %1" : "=v"(dst) : "a"(src))
#define VPIN(dst, src) asm volatile("v_mov_b32 %0, %1" : "=v"(dst) : "v"(src))

// Raw barrier: LDS-visibility only (no vmcnt drain; in-flight vmem rides
// across; its waits land at first use).
#define BAR() do { \
    __builtin_amdgcn_sched_barrier(0); \
    asm volatile("s_waitcnt lgkmcnt(0)" ::: "memory"); \
    __builtin_amdgcn_s_barrier(); \
    __builtin_amdgcn_sched_barrier(0); } while (0)

static __device__ __forceinline__ unsigned long long memrealtime() {
    unsigned long long v;
    asm volatile("s_memrealtime %0\n\ts_waitcnt lgkmcnt(0)"
                 : "=s"(v) :: "memory");
    return v;
}

// ---------------------------------------------------------------------------
// Kernel A: FrameRateNet + gi_cond precompute (unchanged, passing).
// ---------------------------------------------------------------------------
__global__ __launch_bounds__(128) void frn_kernel(
    const float* __restrict__ feat,
    const float* __restrict__ w1,
    const float* __restrict__ b1,
    const float* __restrict__ w2,
    const float* __restrict__ b2,
    const float* __restrict__ fw1,
    const float* __restrict__ fb1,
    const float* __restrict__ fw2,
    const float* __restrict__ fb2,
    const float* __restrict__ wi,
    const float* __restrict__ bi,
    float* __restrict__ gic)
{
    const int bf = blockIdx.x;
    const int b = bf >> 6;
    const int f = bf & 63;
    const int o = threadIdx.x;

    __shared__ float sfeat[5][ND];
    __shared__ float sc1[3][128];
    __shared__ float sc2[128];
    __shared__ float sc3[128];
    __shared__ float scond[128];

    for (int i = o; i < 5 * ND; i += 128) {
        int ff = f - 2 + i / ND;
        int c = i % ND;
        sfeat[i / ND][c] = (ff >= 0 && ff < NF) ? feat[((size_t)b * NF + ff) * ND + c] : 0.f;
    }
    __syncthreads();

    for (int df = 0; df < 3; ++df) {
        int fp = f - 1 + df;
        if (fp >= 0 && fp < NF) {
            float acc = b1[o];
            for (int k = 0; k < 3; ++k)
                for (int c = 0; c < ND; ++c)
                    acc += sfeat[df + k][c] * w1[(k * ND + c) * 128 + o];
            sc1[df][o] = tanhf(acc);
        } else {
            sc1[df][o] = 0.f;
        }
    }
    __syncthreads();

    {
        float acc = b2[o];
        for (int k = 0; k < 3; ++k)
            for (int c = 0; c < 128; ++c)
                acc += sc1[k][c] * w2[(k * 128 + c) * 128 + o];
        sc2[o] = tanhf(acc);
    }
    __syncthreads();
    {
        float acc = fb1[o];
        for (int c = 0; c < 128; ++c) acc += sc2[c] * fw1[c * 128 + o];
        sc3[o] = tanhf(acc);
    }
    __syncthreads();
    {
        float acc = fb2[o];
        for (int c = 0; c < 128; ++c) acc += sc3[c] * fw2[c * 128 + o];
        scond[o] = tanhf(acc);
    }
    __syncthreads();

    for (int r = 0; r < 6; ++r) {
        int j = o + 128 * r;
        float acc = bi[j];
        const float* wr = wi + (size_t)j * 129 + 1;
        for (int c = 0; c < 128; ++c) acc += scond[c] * wr[c];
        gic[(size_t)bf * NG + j] = acc;
    }
}

// ---------------------------------------------------------------------------
// Kernel B: AR loop. 64 blocks (b = bid&7, j = bid>>3), 512 threads.
// ---------------------------------------------------------------------------
__global__ __launch_bounds__(512, 2) void ar_kernel(
    const float* __restrict__ gic,    // (8*64, 768)
    const float* __restrict__ wh,     // (768,256) fp32
    const float* __restrict__ ow,     // (256,256) [c][o] native
    const float* __restrict__ wi,     // (768,129) — need column 0
    const float* __restrict__ bh,     // (768,)
    const float* __restrict__ ob,     // (256,)
    float* __restrict__ wav_out,      // (8, 10240)
    float* __restrict__ logits_out,   // (8, 10240, 256)
    unsigned long long* __restrict__ hxp,  // [8][2][768] packed {tag, gh}
    char* __restrict__ wsraw,         // workspace base (probe regions)
    unsigned long long wssz)          // workspace size
{
    const int bid = blockIdx.x;
    const int b = bid & 7;            // batch
    const int j = bid >> 3;           // CU index within batch, 0..7
    const int t = threadIdx.x;
    const int qq = t >> 4;            // 0..31: local gh row (unit 32j+qq)
    const int ss = t & 15;            // K-chunk of 16 cols (low 4 lane bits)
    const int og = t >> 3;            // 0..63: o-group of 4 (pl)
    const int c8 = t & 7;             // c-chunk of 32 (pl)

    __shared__ __align__(16) float hsp[16 * 20];   // h (full, local), skewed
    __shared__ __align__(16) float pl[8][260];     // logits partials, +4 pad
    __shared__ float sgi[NG];                      // gic frame stage
    __shared__ float candv[4];
    __shared__ int   candi[4];

    // ---- W_h share -> 48 AGPRs: rows {g, g+256, g+512}, g=32j+qq ----
    float A0[16], A1[16], A2[16];
    {
        const float4* wb = (const float4*)wh;      // row = 64 float4
        size_t r0 = (size_t)(32 * j + qq) * 64 + ss * 4;
        #pragma unroll
        for (int i = 0; i < 4; ++i) {
            float4 x0 = wb[r0 + i];
            AG_W(A0[4*i+0], x0.x); AG_W(A0[4*i+1], x0.y);
            AG_W(A0[4*i+2], x0.z); AG_W(A0[4*i+3], x0.w);
        }
        #pragma unroll
        for (int i = 0; i < 4; ++i) {
            float4 x1 = wb[r0 + 256 * 64 + i];
            AG_W(A1[4*i+0], x1.x); AG_W(A1[4*i+1], x1.y);
            AG_W(A1[4*i+2], x1.z); AG_W(A1[4*i+3], x1.w);
        }
        #pragma unroll
        for (int i = 0; i < 4; ++i) {
            float4 x2 = wb[r0 + 512 * 64 + i];
            AG_W(A2[4*i+0], x2.x); AG_W(A2[4*i+1], x2.y);
            AG_W(A2[4*i+2], x2.z); AG_W(A2[4*i+3], x2.w);
        }
    }
    // ---- FULL out_w -> 128 pinned VGPRs: OW4[i] = ow[c8*32+i][og*4..+3] ----
    float4 OW4[32];
    {
        const float4* op = (const float4*)ow;      // row c = 64 float4
        #pragma unroll
        for (int i = 0; i < 32; ++i) {
            float4 x = op[(size_t)(c8 * 32 + i) * 64 + og];
            VPIN(OW4[i].x, x.x); VPIN(OW4[i].y, x.y);
            VPIN(OW4[i].z, x.z); VPIN(OW4[i].w, x.w);
        }
    }

    // ---- per-thread scalars: thread t<256 owns gate unit u=t in D ----
    float bh_r = 0, bh_z = 0, bh_n = 0, wi_r = 0, wi_z = 0, wi_n = 0, ob_o = 0;
    if (t < NH) {
        bh_r = bh[t]; bh_z = bh[t + 256]; bh_n = bh[t + 512];
        wi_r = wi[(size_t)t * 129];
        wi_z = wi[(size_t)(t + 256) * 129];
        wi_n = wi[(size_t)(t + 512) * 129];
        ob_o = ob[t];
        hsp[HLAY(t)] = 0.f;
    }
    float prev = 0.f, yacc = 0.f;
    unsigned spintot = 0;
    __syncthreads();

    const float* gf = gic + (size_t)b * NF * NG;   // advances per frame
    float* lob = logits_out + (size_t)b * NT * NH;
    float* wob = wav_out + (size_t)b * NT;
    unsigned long long* hxb = hxp + (size_t)b * 2 * NSLOT;
    int fcnt = 0;

    for (int st = 0; st <= NT; ++st) {
        // ---- frame staging: gic -> LDS once per 160 steps ----
        if (st < NT && fcnt == 0) {
            for (int i = t; i < NG; i += 512) sgi[i] = gf[i];
        }

        // ---- Phase A1: gh rows for own 32 units; post ASAP (tag st+1) ----
        if (st < NT) {
            const float4* h4 = (const float4*)hsp;
            float a0 = 0.f, a1 = 0.f, a2 = 0.f;
            #pragma unroll
            for (int i = 0; i < 4; ++i) {
                float4 hv = h4[ss * 5 + i];
                float w;
                AG_R(w, A0[4*i+0]); a0 += w * hv.x;
                AG_R(w, A0[4*i+1]); a0 += w * hv.y;
                AG_R(w, A0[4*i+2]); a0 += w * hv.z;
                AG_R(w, A0[4*i+3]); a0 += w * hv.w;
                AG_R(w, A1[4*i+0]); a1 += w * hv.x;
                AG_R(w, A1[4*i+1]); a1 += w * hv.y;
                AG_R(w, A1[4*i+2]); a1 += w * hv.z;
                AG_R(w, A1[4*i+3]); a1 += w * hv.w;
                AG_R(w, A2[4*i+0]); a2 += w * hv.x;
                AG_R(w, A2[4*i+1]); a2 += w * hv.y;
                AG_R(w, A2[4*i+2]); a2 += w * hv.z;
                AG_R(w, A2[4*i+3]); a2 += w * hv.w;
            }
            #pragma unroll
            for (int d = 1; d <= 8; d <<= 1) {
                a0 += __shfl_xor(a0, d);
                a1 += __shfl_xor(a1, d);
                a2 += __shfl_xor(a2, d);
            }
            if (ss < 3) {
                float gv = (ss == 0) ? a0 : ((ss == 1) ? a1 : a2);
                unsigned long long pk =
                    ((unsigned long long)(unsigned)(st + 1) << 32)
                    | (unsigned long long)__float_as_uint(gv);
                (void)__hip_atomic_exchange(
                    &hxb[(size_t)(st & 1) * NSLOT + (ss << 8) + 32 * j + qq],
                    pk, __ATOMIC_RELAXED, AGENT);
            }
            __builtin_amdgcn_sched_barrier(0);   // keep posts ahead of pl work
        }

        // ---- Phase A2: logits partials for h_{st-1} (runs at st==NT too) ----
        if (st > 0) {
            const float4* h4 = (const float4*)hsp;
            float4 acc = {0.f, 0.f, 0.f, 0.f};
            #pragma unroll
            for (int i = 0; i < 8; ++i) {
                float4 hv = h4[(c8 * 2 + (i >> 2)) * 5 + (i & 3)];
                acc.x += hv.x * OW4[4*i+0].x; acc.y += hv.x * OW4[4*i+0].y;
                acc.z += hv.x * OW4[4*i+0].z; acc.w += hv.x * OW4[4*i+0].w;
                acc.x += hv.y * OW4[4*i+1].x; acc.y += hv.y * OW4[4*i+1].y;
                acc.z += hv.y * OW4[4*i+1].z; acc.w += hv.y * OW4[4*i+1].w;
                acc.x += hv.z * OW4[4*i+2].x; acc.y += hv.z * OW4[4*i+2].y;
                acc.z += hv.z * OW4[4*i+2].z; acc.w += hv.z * OW4[4*i+2].w;
                acc.x += hv.w * OW4[4*i+3].x; acc.y += hv.w * OW4[4*i+3].y;
                acc.z += hv.w * OW4[4*i+3].z; acc.w += hv.w * OW4[4*i+3].w;
            }
            *(float4*)&pl[c8][og * 4] = acc;
        }
        BAR();   // b1 (LDS only; posts stay in flight, no producer drain)

        // ---- preload gh (latency hides under B+C; wait lands in D) ----
        unsigned long long g0 = 0, g1 = 0, g2 = 0;
        if (st < NT && t < NH) {
            unsigned long long* hb = hxb + (size_t)(st & 1) * NSLOT;
            g0 = __hip_atomic_load(&hb[t], __ATOMIC_RELAXED, AGENT);
            g1 = __hip_atomic_load(&hb[NH + t], __ATOMIC_RELAXED, AGENT);
            g2 = __hip_atomic_load(&hb[2 * NH + t], __ATOMIC_RELAXED, AGENT);
        }

        // ---- Phase B: finalize logits (keep in reg!), wave argmax ----
        float lgs = 0.f;
        if (st > 0 && t < NH) {
            float lg = ob_o;
            #pragma unroll
            for (int c = 0; c < 8; ++c) lg += pl[c][t];
            lgs = lg;                       // store deferred to post-D
            float bv = lg; int bi_ = t;
            #pragma unroll
            for (int d = 32; d > 0; d >>= 1) {
                float ov = __shfl_down(bv, d);
                int   oi = __shfl_down(bi_, d);
                if (ov > bv || (ov == bv && oi < bi_)) { bv = ov; bi_ = oi; }
            }
            if ((t & 63) == 0) { candv[t >> 6] = bv; candi[t >> 6] = bi_; }
        }
        BAR();   // b2

        // ---- Phase C: sample (all threads, identical everywhere) ----
        if (st > 0) {
            float mv = candv[0]; int mi = candi[0];
            #pragma unroll
            for (int w = 1; w < 4; ++w) {
                float ov = candv[w]; int oi = candi[w];
                if (ov > mv || (ov == mv && oi < mi)) { mv = ov; mi = oi; }
            }
            float v = ((float)mi + 0.5f) * (1.f / 128.f) - 1.f;
            float av = fabsf(v);
            float mag = (exp2f(8.f * av) - 1.f) * (1.f / 255.f);
            float smp = (v >= 0.f) ? mag : -mag;
            prev = smp;
            yacc = smp + 0.97f * yacc;      // store deferred to post-D
        }

        // ---- Phase D: ALL 256 gate units, redundantly on every CU ----
        if (st < NT && t < NH) {
            const unsigned tag = (unsigned)(st + 1);
            unsigned long long* hb = hxb + (size_t)(st & 1) * NSLOT;
            // materialize preloads: the only fresh vmem in this wave's queue
            // is the 3 preloads (stores were deferred past this point last
            // iter, so their acks are ~a full step old).
            asm volatile("s_waitcnt vmcnt(0)"
                         : "+v"(g0), "+v"(g1), "+v"(g2) :: "memory");
            __builtin_amdgcn_sched_barrier(0);
            int spin = 0;
            while (((unsigned)(g0 >> 32) != tag) |
                   ((unsigned)(g1 >> 32) != tag) |
                   ((unsigned)(g2 >> 32) != tag)) {
                ++spin; ++spintot;
                if ((spin & 3) == 3) __builtin_amdgcn_s_sleep(1);
                if ((unsigned)(g0 >> 32) != tag)
                    g0 = __hip_atomic_load(&hb[t], __ATOMIC_RELAXED, AGENT);
                if ((unsigned)(g1 >> 32) != tag)
                    g1 = __hip_atomic_load(&hb[NH + t], __ATOMIC_RELAXED, AGENT);
                if ((unsigned)(g2 >> 32) != tag)
                    g2 = __hip_atomic_load(&hb[2 * NH + t], __ATOMIC_RELAXED, AGENT);
            }
            float ghr = __uint_as_float((unsigned)g0);
            float ghz = __uint_as_float((unsigned)g1);
            float ghn = __uint_as_float((unsigned)g2);
            float sr = sgi[t]          + wi_r * prev + bh_r + ghr;
            float sz = sgi[t + NH]     + wi_z * prev + bh_z + ghz;
            float ni = sgi[t + 2 * NH] + wi_n * prev;
            float nh = bh_n + ghn;
            float r = 1.f / (1.f + expf(-sr));
            float z = 1.f / (1.f + expf(-sz));
            float n = tanhf(ni + r * nh);
            int hl = HLAY(t);
            hsp[hl] = (1.f - z) * n + z * hsp[hl];
        }

        // ---- deferred global stores: OUT of the D wait-window ----
        if (st > 0) {
            if (t < NH && (t >> 5) == j) lob[(size_t)(st - 1) * NH + t] = lgs;
            if (j == 0 && t == 0)        wob[st - 1] = yacc;
        }
        BAR();   // b3

        if (st < NT) {
            if (++fcnt == FS) { fcnt = 0; gf += NG; }
        }
    }

    // ---- diagnostics (block 0 only): clock + retry flag -> WRITE_SIZE ----
    if (bid == 0) {
        unsigned mhz = 0;
        if (t < 64) {
            // 2048*64 = 131072 dependent v_fma, 4 cy each (m07) -> 524288 cy
            float x = 1.0f;
            float ca = 1.0000001f, cb = -1e-9f;
            unsigned long long r0 = memrealtime();
            for (int it = 0; it < 2048; ++it) {
                #pragma unroll
                for (int u = 0; u < 64; ++u)
                    asm volatile("v_fma_f32 %0, %0, %1, %2"
                                 : "+v"(x) : "v"(ca), "v"(cb));
            }
            unsigned long long r1 = memrealtime();
            asm volatile("" :: "v"(x));          // keep chain live
            unsigned long long drt = r1 - r0;    // 100 MHz ticks
            if (drt == 0) drt = 1;
            mhz = (unsigned)((524288ull * 100ull + (drt >> 1)) / drt);
            if (mhz > 3200) mhz = 3200;
        }
        if (t == 0 && wssz >= (20ull << 20)) {
            // lines = 16*MHz + 4096 + 131072*flag, 64B apart, sc1 stores
            // (write-through to HBM counter; R7 proved 1:1 accounting).
            unsigned nl = 16u * mhz + 4096u + (spintot >= 10240u ? 131072u : 0u);
            char* wp = wsraw + (4ull << 20);
            float one = 1.0f;
            for (unsigned i = 0; i < nl; ++i) {
                asm volatile("global_store_dword %0, %1, off sc0 sc1"
                             :: "v"((float*)(wp + (size_t)i * 64)), "v"(one)
                             : "memory");
            }
            asm volatile("s_waitcnt vmcnt(0)" ::: "memory");
        }
    }
}

// ---------------------------------------------------------------------------
extern "C" void kernel_launch(void* const* d_in, const int* in_sizes, int n_in,
                              void* d_out, int out_size, void* d_ws, size_t ws_size,
                              hipStream_t stream) {
    (void)in_sizes; (void)n_in; (void)out_size;

    const float* feat = (const float*)d_in[0];
    const float* c1w  = (const float*)d_in[1];
    const float* c1b  = (const float*)d_in[2];
    const float* c2w  = (const float*)d_in[3];
    const float* c2b  = (const float*)d_in[4];
    const float* f1w  = (const float*)d_in[5];
    const float* f1b  = (const float*)d_in[6];
    const float* f2w  = (const float*)d_in[7];
    const float* f2b  = (const float*)d_in[8];
    const float* gwi  = (const float*)d_in[9];
    const float* gwh  = (const float*)d_in[10];
    const float* gbi  = (const float*)d_in[11];
    const float* gbh  = (const float*)d_in[12];
    const float* outw = (const float*)d_in[13];
    const float* outb = (const float*)d_in[14];

    // workspace layout
    char* ws = (char*)d_ws;
    float* gic = (float*)ws;                                        // 1,572,864 B
    unsigned long long* hxp = (unsigned long long*)(ws + 1572864);  // 98,304 B
    // probe region: [ws+4MB, ws+4MB+~12MB), gated on ws_size >= 20MB.
    // tag protocol: harness poison (0xAA bytes) never matches any tag
    // (st+1 <= 10240); stale same-tag data from a prior identical launch is
    // bitwise identical (deterministic compute), so no memset is required.

    float* wav    = (float*)d_out;                 // (8,10240,1)
    float* logits = (float*)d_out + NB * NT;       // (8,10240,256)

    frn_kernel<<<dim3(NB * NF), dim3(128), 0, stream>>>(
        feat, c1w, c1b, c2w, c2b, f1w, f1b, f2w, f2b, gwi, gbi, gic);
    ar_kernel<<<dim3(64), dim3(512), 0, stream>>>(
        gic, gwh, outw, gwi, gbh, outb, wav, logits, hxp,
        ws, (unsigned long long)ws_size);
}